// Round 6
// baseline (543.267 us; speedup 1.0000x reference)
//
#include <hip/hip_runtime.h>

namespace {

constexpr int T = 1024;
constexpr int B = 1024;
constexpr int L = 10;
constexpr int H = 10;
constexpr int NTHREADS = 128;           // 2 full waves; 100 active threads
constexpr int NSTEP = T + L - 1;        // 1033
constexpr int BH = B * H;

using v2f = __attribute__((ext_vector_type(2))) float;

__device__ __forceinline__ v2f v2fma(v2f a, v2f b, v2f c) {
    return __builtin_elementwise_fma(a, b, c);   // -> v_pk_fma_f32
}

// Opaque identity: makes the value's def un-rematerializable, forcing the
// register allocator to keep it resident instead of re-issuing the
// (invariant) global load inside the step loop. Round-5 evidence: VGPR=88
// with an 84-float weight set and unchanged step latency => remat.
__device__ __forceinline__ void pin(v2f& v) { asm volatile("" : "+v"(v)); }
__device__ __forceinline__ void pin(float& v) { asm volatile("" : "+v"(v)); }

// v_exp-based fast activations; saturation-safe at +/-inf.
__device__ __forceinline__ float sigmoid_f(float x) {
    return __builtin_amdgcn_rcpf(1.0f + __expf(-x));
}
__device__ __forceinline__ float tanh_f(float x) {
    return 1.0f - 2.0f * __builtin_amdgcn_rcpf(1.0f + __expf(2.0f * x));
}

__global__
__attribute__((amdgpu_flat_work_group_size(NTHREADS, NTHREADS)))
__attribute__((amdgpu_waves_per_eu(2, 2)))   // 256-VGPR budget, 2 waves/EU
void lstm_pipeline(const float* __restrict__ x,    // [T,B,H]
                   const float* __restrict__ hp,   // [L,B,H]
                   const float* __restrict__ cp,   // [L,B,H]
                   const float* __restrict__ Wih,  // [L,4H,H]
                   const float* __restrict__ Whh,  // [L,4H,H]
                   const float* __restrict__ bih,  // [L,4H]
                   const float* __restrict__ bhh,  // [L,4H]
                   float* __restrict__ out,        // [T,B,H]
                   float* __restrict__ hn,         // [L,B,H]
                   float* __restrict__ cn)         // [L,B,H]
{
    // buf[l] = input to layer l (l=0: staged x; l>=1: h of layer l-1).
    // s-parity double buffer; rows padded 10->12 floats for float4 reads.
    __shared__ __align__(16) float buf[L + 1][2][12];

    const int tid = threadIdx.x;
    const bool active = tid < L * H;
    const int l = active ? tid / H : L - 1;   // layer 0..9
    const int j = active ? tid % H : H - 1;   // hidden unit 0..9
    const int b = blockIdx.x;                 // one batch element per block
    const int boff = b * H + j;

    // Per-thread weights as float2 pairs (torch gate order i,f,g,o).
    v2f wi2[4][5], wh2[4][5];
    float bias[4];
    float c = 0.0f, xa = 0.0f;

    if (active) {
        #pragma unroll
        for (int g = 0; g < 4; ++g) {
            const size_t row = (size_t)(l * 4 * H + g * H + j);
            const float* wr = Wih + row * H;
            const float* hr = Whh + row * H;
            #pragma unroll
            for (int p = 0; p < 5; ++p) {
                v2f a; a[0] = wr[2 * p]; a[1] = wr[2 * p + 1]; wi2[g][p] = a;
                v2f d; d[0] = hr[2 * p]; d[1] = hr[2 * p + 1]; wh2[g][p] = d;
            }
            bias[g] = bih[row] + bhh[row];
        }
        // Pin all loop-invariant weights into VGPRs (defeat load remat).
        #pragma unroll
        for (int g = 0; g < 4; ++g) {
            #pragma unroll
            for (int p = 0; p < 5; ++p) { pin(wi2[g][p]); pin(wh2[g][p]); }
            pin(bias[g]);
        }
        c = cp[(l * B + b) * H + j];
        // h(-1): layer l reads it at s=l from parity (l-1)&1.
        buf[l + 1][(l & 1) ^ 1][j] = hp[(l * B + b) * H + j];
        if (l == 0) {
            buf[0][1][j] = x[boff];          // x(0), read at s=0 (parity 1)
            xa = x[BH + boff];               // x(1), staged at s=0
        }
    }
    __syncthreads();

    auto step = [&](int s, int wp, int rp) {
        if (active) {
            const int t = s - l;
            if (t >= 0 && t < T) {
                float xin[12], hin[12];
                {
                    float4* xv = (float4*)xin;
                    float4* hv = (float4*)hin;
                    const float4* xs = (const float4*)&buf[l][rp][0];
                    const float4* hs = (const float4*)&buf[l + 1][rp][0];
                    xv[0] = xs[0]; xv[1] = xs[1]; xv[2] = xs[2];
                    hv[0] = hs[0]; hv[1] = hs[1]; hv[2] = hs[2];
                }

                v2f acc2[4];
                #pragma unroll
                for (int g = 0; g < 4; ++g) {
                    v2f a; a[0] = bias[g]; a[1] = 0.0f; acc2[g] = a;
                }
                #pragma unroll
                for (int p = 0; p < 5; ++p) {
                    v2f xp; xp[0] = xin[2 * p]; xp[1] = xin[2 * p + 1];
                    #pragma unroll
                    for (int g = 0; g < 4; ++g) acc2[g] = v2fma(wi2[g][p], xp, acc2[g]);
                }
                #pragma unroll
                for (int p = 0; p < 5; ++p) {
                    v2f hh; hh[0] = hin[2 * p]; hh[1] = hin[2 * p + 1];
                    #pragma unroll
                    for (int g = 0; g < 4; ++g) acc2[g] = v2fma(wh2[g][p], hh, acc2[g]);
                }

                const float ig = sigmoid_f(acc2[0][0] + acc2[0][1]);
                const float fg = sigmoid_f(acc2[1][0] + acc2[1][1]);
                const float gg = tanh_f(acc2[2][0] + acc2[2][1]);
                const float og = sigmoid_f(acc2[3][0] + acc2[3][1]);
                c = fmaf(fg, c, ig * gg);
                const float hval = og * tanh_f(c);

                buf[l + 1][wp][j] = hval;
                if (l == L - 1) {
                    out[(size_t)t * BH + boff] = hval;
                }
            }
            // Layer 0: stage x(s+1) (loaded one step ago), issue x(s+2).
            if (l == 0 && (s + 1) < T) {
                buf[0][wp][j] = xa;
                if ((s + 2) < T) xa = x[(size_t)(s + 2) * BH + boff];
            }
        }
        __syncthreads();
    };

    // Unroll by 2 so LDS parity indices are compile-time constants.
    for (int sb = 0; sb < NSTEP + 1; sb += 2) {   // covers s=0..1033 (1033 pads out)
        step(sb, 0, 1);
        step(sb + 1, 1, 0);
    }

    // Finals: layer l's h(T-1) was written at s=T-1+l -> parity (l+1)&1 (T even).
    if (active) {
        hn[(l * B + b) * H + j] = buf[l + 1][(l + 1) & 1][j];
        cn[(l * B + b) * H + j] = c;
    }
}

} // namespace

extern "C" void kernel_launch(void* const* d_in, const int* in_sizes, int n_in,
                              void* d_out, int out_size, void* d_ws, size_t ws_size,
                              hipStream_t stream) {
    (void)in_sizes; (void)n_in; (void)d_ws; (void)ws_size; (void)out_size;
    const float* x   = (const float*)d_in[0];
    const float* hp  = (const float*)d_in[1];
    const float* cp  = (const float*)d_in[2];
    const float* Wih = (const float*)d_in[3];
    const float* Whh = (const float*)d_in[4];
    const float* bih = (const float*)d_in[5];
    const float* bhh = (const float*)d_in[6];

    float* out = (float*)d_out;
    float* hn  = out + (size_t)T * B * H;
    float* cn  = hn + (size_t)L * B * H;

    lstm_pipeline<<<dim3(B), dim3(NTHREADS), 0, stream>>>(
        x, hp, cp, Wih, Whh, bih, bhh, out, hn, cn);
}